// Round 1
// baseline (1178.674 us; speedup 1.0000x reference)
//
#include <hip/hip_runtime.h>

// ---------------------------------------------------------------------------
// TOD -> sky map scatter (map-making P^T), B batches, 3 Stokes (I,Q,U).
// out[b][p][k] = (sum_{s: pix[s]==p} tod[b][s] * w[s][k]) / cov[p]
// ---------------------------------------------------------------------------

__global__ void zero_out_kernel(float4* __restrict__ out, int n4) {
    int i = blockIdx.x * blockDim.x + threadIdx.x;
    int stride = gridDim.x * blockDim.x;
    for (; i < n4; i += stride) out[i] = make_float4(0.f, 0.f, 0.f, 0.f);
}

__global__ void scatter_kernel(const float* __restrict__ tod,      // [B][S]
                               const float* __restrict__ weights,  // [S][3]
                               const int*   __restrict__ pix,      // [S]
                               float* __restrict__ out,            // [B][NPIX][3]
                               int S, int npix, int B) {
    int i = blockIdx.x * blockDim.x + threadIdx.x;
    int stride = gridDim.x * blockDim.x;
    const size_t bstride = (size_t)npix * 3;
    for (int s = i; s < S; s += stride) {
        const int p = pix[s];
        const float w0 = weights[3 * s + 0];
        const float w1 = weights[3 * s + 1];
        const float w2 = weights[3 * s + 2];
        float* o = out + (size_t)p * 3;
        #pragma unroll 4
        for (int b = 0; b < B; ++b) {
            const float t = tod[(size_t)b * S + s];
            float* ob = o + (size_t)b * bstride;
            atomicAdd(ob + 0, t * w0);
            atomicAdd(ob + 1, t * w1);
            atomicAdd(ob + 2, t * w2);
        }
    }
}

__global__ void normalize_kernel(float* __restrict__ out,          // [B][NPIX][3]
                                 const float* __restrict__ cov,    // [NPIX]
                                 int npix, int B) {
    int i = blockIdx.x * blockDim.x + threadIdx.x;
    int stride = gridDim.x * blockDim.x;
    const int total = B * npix;
    for (; i < total; i += stride) {
        const int p = i % npix;  // npix = 196608 = 3<<16: compiler strength-reduces
        const float c = cov[p];
        float* o = out + (size_t)i * 3;
        o[0] = o[0] / c;
        o[1] = o[1] / c;
        o[2] = o[2] / c;
    }
}

extern "C" void kernel_launch(void* const* d_in, const int* in_sizes, int n_in,
                              void* d_out, int out_size, void* d_ws, size_t ws_size,
                              hipStream_t stream) {
    const float* tod     = (const float*)d_in[0];   // [B][S]
    const float* weights = (const float*)d_in[1];   // [S][3]
    const float* cov     = (const float*)d_in[2];   // [NPIX]
    const int*   pix     = (const int*)d_in[3];     // [S]
    float* out = (float*)d_out;                     // [B][NPIX][3]

    const int S    = in_sizes[3];
    const int npix = in_sizes[2];
    const int B    = in_sizes[0] / S;

    const int block = 256;

    // 1) zero the accumulator (d_out is poisoned, not re-zeroed by harness)
    {
        const int n4 = out_size / 4;  // out_size = B*npix*3, divisible by 4
        int grid = (n4 + block - 1) / block;
        if (grid > 2048) grid = 2048;
        zero_out_kernel<<<grid, block, 0, stream>>>((float4*)out, n4);
    }

    // 2) scatter-add all samples
    {
        int grid = (S + block - 1) / block;
        if (grid > 4096) grid = 4096;
        scatter_kernel<<<grid, block, 0, stream>>>(tod, weights, pix, out,
                                                   S, npix, B);
    }

    // 3) coverage normalization
    {
        const int total = B * npix;
        int grid = (total + block - 1) / block;
        if (grid > 2048) grid = 2048;
        normalize_kernel<<<grid, block, 0, stream>>>(out, cov, npix, B);
    }
}

// Round 2
// 200.500 us; speedup vs baseline: 5.8787x; 5.8787x over previous
//
#include <hip/hip_runtime.h>

// ---------------------------------------------------------------------------
// TOD -> sky map scatter (map-making P^T), B batches, 3 Stokes (I,Q,U).
// out[b][p][k] = (sum_{s: pix[s]==p} tod[b][s] * w[s][k]) / cov[p]
//
// Strategy: global-atomic-free counting sort by 256-pixel bucket, then
// per-bucket LDS accumulation. Round-1 counters showed the fabric atomic
// path saturating at ~32 B/atomic x 24M atomics (732 MB WRITE_SIZE).
// ---------------------------------------------------------------------------

constexpr int NB   = 768;    // buckets
constexpr int BW   = 256;    // pixels per bucket (npix must be NB*BW)
constexpr int NBLK = 1024;   // chunking blocks for hist/reorder

// ---------------- fast path kernels ----------------

__global__ void hist_kernel(const int* __restrict__ pix, int S, int chunk,
                            int* __restrict__ hist2d) {
    __shared__ int lh[NB];
    for (int t = threadIdx.x; t < NB; t += blockDim.x) lh[t] = 0;
    __syncthreads();
    const int beg = blockIdx.x * chunk;
    const int end = min(S, beg + chunk);
    for (int j = beg + threadIdx.x; j < end; j += blockDim.x)
        atomicAdd(&lh[pix[j] >> 8], 1);
    __syncthreads();
    for (int t = threadIdx.x; t < NB; t += blockDim.x)
        hist2d[t * NBLK + blockIdx.x] = lh[t];
}

// one block per bucket: exclusive scan of its NBLK per-block counts
__global__ void scan_blocks_kernel(int* __restrict__ hist2d,
                                   int* __restrict__ btotal) {
    __shared__ int sc[NBLK];
    const int bkt = blockIdx.x, tid = threadIdx.x;
    const int v = hist2d[bkt * NBLK + tid];
    sc[tid] = v;
    __syncthreads();
    for (int off = 1; off < NBLK; off <<= 1) {
        int x = (tid >= off) ? sc[tid - off] : 0;
        __syncthreads();
        sc[tid] += x;
        __syncthreads();
    }
    hist2d[bkt * NBLK + tid] = sc[tid] - v;     // exclusive within bucket
    if (tid == NBLK - 1) btotal[bkt] = sc[tid]; // bucket total
}

// single block: exclusive scan of NB bucket totals
__global__ void scan_buckets_kernel(const int* __restrict__ btotal,
                                    int* __restrict__ bbase, int S) {
    __shared__ int sc[NB];
    const int tid = threadIdx.x;
    const int v = btotal[tid];
    sc[tid] = v;
    __syncthreads();
    for (int off = 1; off < NB; off <<= 1) {
        int x = (tid >= off) ? sc[tid - off] : 0;
        __syncthreads();
        sc[tid] += x;
        __syncthreads();
    }
    bbase[tid] = sc[tid] - v;
    if (tid == NB - 1) bbase[NB] = sc[tid]; // == S
}

__global__ void reorder_kernel(const int* __restrict__ pix, int S, int chunk,
                               const int* __restrict__ hist2d,
                               const int* __restrict__ bbase,
                               int* __restrict__ ridx) {
    __shared__ int lbase[NB];
    __shared__ int lcur[NB];
    const int blk = blockIdx.x;
    for (int t = threadIdx.x; t < NB; t += blockDim.x) {
        lbase[t] = bbase[t] + hist2d[t * NBLK + blk];
        lcur[t] = 0;
    }
    __syncthreads();
    const int beg = blk * chunk;
    const int end = min(S, beg + chunk);
    for (int j = beg + threadIdx.x; j < end; j += blockDim.x) {
        const int bkt = pix[j] >> 8;
        const int r = atomicAdd(&lcur[bkt], 1);   // LDS atomic (cheap)
        ridx[lbase[bkt] + r] = j;
    }
}

// one block (256 threads) per bucket: LDS accumulate + fused normalize
__global__ void accum_kernel(const float* __restrict__ tod,      // [4][S]
                             const float* __restrict__ weights,  // [S][3]
                             const float* __restrict__ cov,      // [npix]
                             const int* __restrict__ pix,        // [S]
                             const int* __restrict__ ridx,       // [S] sorted
                             const int* __restrict__ bbase,      // [NB+1]
                             float* __restrict__ out,            // [4][npix][3]
                             int S, int npix) {
    __shared__ float acc[BW * 12];
    const int bkt = blockIdx.x;
    for (int t = threadIdx.x; t < BW * 12; t += blockDim.x) acc[t] = 0.f;
    __syncthreads();
    const int beg = bbase[bkt], end = bbase[bkt + 1];
    for (int i = beg + threadIdx.x; i < end; i += blockDim.x) {
        const int s = ridx[i];
        const int l = pix[s] & (BW - 1);
        const float w0 = weights[3 * s + 0];
        const float w1 = weights[3 * s + 1];
        const float w2 = weights[3 * s + 2];
        float* a = &acc[l * 12];
        #pragma unroll
        for (int q = 0; q < 4; ++q) {
            const float t0 = tod[(size_t)q * S + s];
            atomicAdd(a + q * 3 + 0, t0 * w0);   // ds_add_f32
            atomicAdd(a + q * 3 + 1, t0 * w1);
            atomicAdd(a + q * 3 + 2, t0 * w2);
        }
    }
    __syncthreads();
    const int l = threadIdx.x;                    // blockDim.x == BW
    const int p = bkt * BW + l;
    const float c = cov[p];
    #pragma unroll
    for (int q = 0; q < 4; ++q) {
        const size_t o = ((size_t)q * npix + p) * 3;
        out[o + 0] = acc[l * 12 + q * 3 + 0] / c;
        out[o + 1] = acc[l * 12 + q * 3 + 1] / c;
        out[o + 2] = acc[l * 12 + q * 3 + 2] / c;
    }
}

// ---------------- fallback (round-1 atomic path) ----------------

__global__ void zero_out_kernel(float4* __restrict__ out, int n4) {
    int i = blockIdx.x * blockDim.x + threadIdx.x;
    int stride = gridDim.x * blockDim.x;
    for (; i < n4; i += stride) out[i] = make_float4(0.f, 0.f, 0.f, 0.f);
}

__global__ void scatter_kernel(const float* __restrict__ tod,
                               const float* __restrict__ weights,
                               const int*   __restrict__ pix,
                               float* __restrict__ out,
                               int S, int npix, int B) {
    int i = blockIdx.x * blockDim.x + threadIdx.x;
    int stride = gridDim.x * blockDim.x;
    const size_t bstride = (size_t)npix * 3;
    for (int s = i; s < S; s += stride) {
        const int p = pix[s];
        const float w0 = weights[3 * s + 0];
        const float w1 = weights[3 * s + 1];
        const float w2 = weights[3 * s + 2];
        float* o = out + (size_t)p * 3;
        for (int b = 0; b < B; ++b) {
            const float t = tod[(size_t)b * S + s];
            float* ob = o + (size_t)b * bstride;
            atomicAdd(ob + 0, t * w0);
            atomicAdd(ob + 1, t * w1);
            atomicAdd(ob + 2, t * w2);
        }
    }
}

__global__ void normalize_kernel(float* __restrict__ out,
                                 const float* __restrict__ cov,
                                 int npix, int B) {
    int i = blockIdx.x * blockDim.x + threadIdx.x;
    int stride = gridDim.x * blockDim.x;
    const int total = B * npix;
    for (; i < total; i += stride) {
        const int p = i % npix;
        const float c = cov[p];
        float* o = out + (size_t)i * 3;
        o[0] /= c; o[1] /= c; o[2] /= c;
    }
}

// ---------------- launch ----------------

extern "C" void kernel_launch(void* const* d_in, const int* in_sizes, int n_in,
                              void* d_out, int out_size, void* d_ws, size_t ws_size,
                              hipStream_t stream) {
    const float* tod     = (const float*)d_in[0];   // [B][S]
    const float* weights = (const float*)d_in[1];   // [S][3]
    const float* cov     = (const float*)d_in[2];   // [NPIX]
    const int*   pix     = (const int*)d_in[3];     // [S]
    float* out = (float*)d_out;                     // [B][NPIX][3]

    const int S    = in_sizes[3];
    const int npix = in_sizes[2];
    const int B    = in_sizes[0] / S;

    // ws layout (ints): hist2d[NB*NBLK] | btotal[NB] | bbase[NB+1] | ridx[S]
    const size_t need = ((size_t)NB * NBLK + NB + (NB + 1) + (size_t)S) * sizeof(int);

    if (B == 4 && npix == NB * BW && ws_size >= need) {
        int* hist2d = (int*)d_ws;
        int* btotal = hist2d + (size_t)NB * NBLK;
        int* bbase  = btotal + NB;
        int* ridx   = bbase + (NB + 1);
        const int chunk = (S + NBLK - 1) / NBLK;

        hist_kernel<<<NBLK, 256, 0, stream>>>(pix, S, chunk, hist2d);
        scan_blocks_kernel<<<NB, NBLK, 0, stream>>>(hist2d, btotal);
        scan_buckets_kernel<<<1, NB, 0, stream>>>(btotal, bbase, S);
        reorder_kernel<<<NBLK, 256, 0, stream>>>(pix, S, chunk, hist2d, bbase, ridx);
        accum_kernel<<<NB, BW, 0, stream>>>(tod, weights, cov, pix, ridx, bbase,
                                            out, S, npix);
        return;
    }

    // generic fallback: direct global atomics
    const int block = 256;
    {
        const int n4 = out_size / 4;
        int grid = min((n4 + block - 1) / block, 2048);
        zero_out_kernel<<<grid, block, 0, stream>>>((float4*)out, n4);
    }
    {
        int grid = min((S + block - 1) / block, 4096);
        scatter_kernel<<<grid, block, 0, stream>>>(tod, weights, pix, out, S, npix, B);
    }
    {
        const int total = B * npix;
        int grid = min((total + block - 1) / block, 2048);
        normalize_kernel<<<grid, block, 0, stream>>>(out, cov, npix, B);
    }
}

// Round 3
// 183.645 us; speedup vs baseline: 6.4182x; 1.0918x over previous
//
#include <hip/hip_runtime.h>

// ---------------------------------------------------------------------------
// TOD -> sky map scatter (map-making P^T), B=4 batches, 3 Stokes (I,Q,U).
// out[b][p][k] = (sum_{s: pix[s]==p} tod[b][s] * w[s][k]) / cov[p]
//
// R1: direct global atomics  -> 1178 us (fabric atomic path, 732 MB writes)
// R2: counting-sort + gather -> 200 us  (accum gather = 516 MB fetch: each
//     bucket's samples are ~768 apart in time -> 4 fresh lines per sample)
// R3: carry payload through the sort. Reorder streams tod/weights/pix
//     sequentially and writes 32B records into bucket order; accum streams
//     records coalesced and accumulates in LDS. No global atomics anywhere.
// ---------------------------------------------------------------------------

constexpr int NB   = 768;    // buckets (npix / BW)
constexpr int BW   = 256;    // pixels per bucket
constexpr int NBLK = 512;    // chunking blocks for hist/reorder

// ---------------- sort infrastructure ----------------

__global__ void hist_kernel(const int* __restrict__ pix, int S, int chunk,
                            int* __restrict__ hist2d) {
    __shared__ int lh[NB];
    for (int t = threadIdx.x; t < NB; t += blockDim.x) lh[t] = 0;
    __syncthreads();
    const int beg = blockIdx.x * chunk;
    const int end = min(S, beg + chunk);
    for (int j = beg + threadIdx.x; j < end; j += blockDim.x)
        atomicAdd(&lh[pix[j] >> 8], 1);
    __syncthreads();
    for (int t = threadIdx.x; t < NB; t += blockDim.x)
        hist2d[t * NBLK + blockIdx.x] = lh[t];
}

// one block per bucket: exclusive scan of its NBLK per-block counts
__global__ void scan_blocks_kernel(int* __restrict__ hist2d,
                                   int* __restrict__ btotal) {
    __shared__ int sc[NBLK];
    const int bkt = blockIdx.x, tid = threadIdx.x;
    const int v = hist2d[bkt * NBLK + tid];
    sc[tid] = v;
    __syncthreads();
    for (int off = 1; off < NBLK; off <<= 1) {
        int x = (tid >= off) ? sc[tid - off] : 0;
        __syncthreads();
        sc[tid] += x;
        __syncthreads();
    }
    hist2d[bkt * NBLK + tid] = sc[tid] - v;     // exclusive within bucket
    if (tid == NBLK - 1) btotal[bkt] = sc[tid]; // bucket total
}

// single block: exclusive scan of NB bucket totals
__global__ void scan_buckets_kernel(const int* __restrict__ btotal,
                                    int* __restrict__ bbase, int S) {
    __shared__ int sc[NB];
    const int tid = threadIdx.x;
    const int v = btotal[tid];
    sc[tid] = v;
    __syncthreads();
    for (int off = 1; off < NB; off <<= 1) {
        int x = (tid >= off) ? sc[tid - off] : 0;
        __syncthreads();
        sc[tid] += x;
        __syncthreads();
    }
    bbase[tid] = sc[tid] - v;
    if (tid == NB - 1) bbase[NB] = sc[tid]; // == S
}

// ---------------- R3 fast path: payload reorder + streaming accum ----------

// reorder with payload: record = {lpix(bits), w0,w1,w2, t0,t1,t2,t3} = 32 B
__global__ void reorder_payload_kernel(const float* __restrict__ tod,     // [4][S]
                                       const float* __restrict__ weights, // [S][3]
                                       const int* __restrict__ pix,       // [S]
                                       int S, int chunk,
                                       const int* __restrict__ hist2d,
                                       const int* __restrict__ bbase,
                                       float4* __restrict__ rec) {        // [S][2]
    __shared__ int lbase[NB];
    __shared__ int lcur[NB];
    const int blk = blockIdx.x;
    for (int t = threadIdx.x; t < NB; t += blockDim.x) {
        lbase[t] = bbase[t] + hist2d[t * NBLK + blk];
        lcur[t] = 0;
    }
    __syncthreads();
    const int beg = blk * chunk;
    const int end = min(S, beg + chunk);
    for (int j = beg + threadIdx.x; j < end; j += blockDim.x) {
        const int p   = pix[j];
        const int bkt = p >> 8;
        const int r   = atomicAdd(&lcur[bkt], 1);        // LDS atomic
        const int dst = lbase[bkt] + r;
        float4 a, b;
        a.x = __int_as_float(p & (BW - 1));
        a.y = weights[3 * j + 0];
        a.z = weights[3 * j + 1];
        a.w = weights[3 * j + 2];
        b.x = tod[(size_t)0 * S + j];
        b.y = tod[(size_t)1 * S + j];
        b.z = tod[(size_t)2 * S + j];
        b.w = tod[(size_t)3 * S + j];
        rec[(size_t)dst * 2 + 0] = a;
        rec[(size_t)dst * 2 + 1] = b;
    }
}

// one block (256 threads) per bucket: stream records, LDS accumulate,
// fused coverage normalize, coalesced output write.
__global__ void accum_rec_kernel(const float4* __restrict__ rec,   // [S][2]
                                 const float* __restrict__ cov,    // [npix]
                                 const int* __restrict__ bbase,    // [NB+1]
                                 float* __restrict__ out,          // [4][npix][3]
                                 int npix) {
    __shared__ float acc[BW * 12];
    const int bkt = blockIdx.x;
    for (int t = threadIdx.x; t < BW * 12; t += blockDim.x) acc[t] = 0.f;
    __syncthreads();
    const int beg = bbase[bkt], end = bbase[bkt + 1];
    for (int i = beg + threadIdx.x; i < end; i += blockDim.x) {
        const float4 a = rec[(size_t)i * 2 + 0];
        const float4 b = rec[(size_t)i * 2 + 1];
        const int l = __float_as_int(a.x);
        float* ap = &acc[l * 12];
        atomicAdd(ap + 0,  b.x * a.y);
        atomicAdd(ap + 1,  b.x * a.z);
        atomicAdd(ap + 2,  b.x * a.w);
        atomicAdd(ap + 3,  b.y * a.y);
        atomicAdd(ap + 4,  b.y * a.z);
        atomicAdd(ap + 5,  b.y * a.w);
        atomicAdd(ap + 6,  b.z * a.y);
        atomicAdd(ap + 7,  b.z * a.z);
        atomicAdd(ap + 8,  b.z * a.w);
        atomicAdd(ap + 9,  b.w * a.y);
        atomicAdd(ap + 10, b.w * a.z);
        atomicAdd(ap + 11, b.w * a.w);
    }
    __syncthreads();
    const int l = threadIdx.x;                    // blockDim.x == BW
    const int p = bkt * BW + l;
    const float rc = 1.0f / cov[p];
    #pragma unroll
    for (int q = 0; q < 4; ++q) {
        const size_t o = ((size_t)q * npix + p) * 3;
        out[o + 0] = acc[l * 12 + q * 3 + 0] * rc;
        out[o + 1] = acc[l * 12 + q * 3 + 1] * rc;
        out[o + 2] = acc[l * 12 + q * 3 + 2] * rc;
    }
}

// ---------------- R2 fallback path: index reorder + gather accum -----------

__global__ void reorder_kernel(const int* __restrict__ pix, int S, int chunk,
                               const int* __restrict__ hist2d,
                               const int* __restrict__ bbase,
                               int* __restrict__ ridx) {
    __shared__ int lbase[NB];
    __shared__ int lcur[NB];
    const int blk = blockIdx.x;
    for (int t = threadIdx.x; t < NB; t += blockDim.x) {
        lbase[t] = bbase[t] + hist2d[t * NBLK + blk];
        lcur[t] = 0;
    }
    __syncthreads();
    const int beg = blk * chunk;
    const int end = min(S, beg + chunk);
    for (int j = beg + threadIdx.x; j < end; j += blockDim.x) {
        const int bkt = pix[j] >> 8;
        const int r = atomicAdd(&lcur[bkt], 1);
        ridx[lbase[bkt] + r] = j;
    }
}

__global__ void accum_kernel(const float* __restrict__ tod,
                             const float* __restrict__ weights,
                             const float* __restrict__ cov,
                             const int* __restrict__ pix,
                             const int* __restrict__ ridx,
                             const int* __restrict__ bbase,
                             float* __restrict__ out,
                             int S, int npix) {
    __shared__ float acc[BW * 12];
    const int bkt = blockIdx.x;
    for (int t = threadIdx.x; t < BW * 12; t += blockDim.x) acc[t] = 0.f;
    __syncthreads();
    const int beg = bbase[bkt], end = bbase[bkt + 1];
    for (int i = beg + threadIdx.x; i < end; i += blockDim.x) {
        const int s = ridx[i];
        const int l = pix[s] & (BW - 1);
        const float w0 = weights[3 * s + 0];
        const float w1 = weights[3 * s + 1];
        const float w2 = weights[3 * s + 2];
        float* a = &acc[l * 12];
        #pragma unroll
        for (int q = 0; q < 4; ++q) {
            const float t0 = tod[(size_t)q * S + s];
            atomicAdd(a + q * 3 + 0, t0 * w0);
            atomicAdd(a + q * 3 + 1, t0 * w1);
            atomicAdd(a + q * 3 + 2, t0 * w2);
        }
    }
    __syncthreads();
    const int l = threadIdx.x;
    const int p = bkt * BW + l;
    const float c = cov[p];
    #pragma unroll
    for (int q = 0; q < 4; ++q) {
        const size_t o = ((size_t)q * npix + p) * 3;
        out[o + 0] = acc[l * 12 + q * 3 + 0] / c;
        out[o + 1] = acc[l * 12 + q * 3 + 1] / c;
        out[o + 2] = acc[l * 12 + q * 3 + 2] / c;
    }
}

// ---------------- generic fallback: direct atomics -------------------------

__global__ void zero_out_kernel(float4* __restrict__ out, int n4) {
    int i = blockIdx.x * blockDim.x + threadIdx.x;
    int stride = gridDim.x * blockDim.x;
    for (; i < n4; i += stride) out[i] = make_float4(0.f, 0.f, 0.f, 0.f);
}

__global__ void scatter_kernel(const float* __restrict__ tod,
                               const float* __restrict__ weights,
                               const int*   __restrict__ pix,
                               float* __restrict__ out,
                               int S, int npix, int B) {
    int i = blockIdx.x * blockDim.x + threadIdx.x;
    int stride = gridDim.x * blockDim.x;
    const size_t bstride = (size_t)npix * 3;
    for (int s = i; s < S; s += stride) {
        const int p = pix[s];
        const float w0 = weights[3 * s + 0];
        const float w1 = weights[3 * s + 1];
        const float w2 = weights[3 * s + 2];
        float* o = out + (size_t)p * 3;
        for (int b = 0; b < B; ++b) {
            const float t = tod[(size_t)b * S + s];
            float* ob = o + (size_t)b * bstride;
            atomicAdd(ob + 0, t * w0);
            atomicAdd(ob + 1, t * w1);
            atomicAdd(ob + 2, t * w2);
        }
    }
}

__global__ void normalize_kernel(float* __restrict__ out,
                                 const float* __restrict__ cov,
                                 int npix, int B) {
    int i = blockIdx.x * blockDim.x + threadIdx.x;
    int stride = gridDim.x * blockDim.x;
    const int total = B * npix;
    for (; i < total; i += stride) {
        const int p = i % npix;
        const float c = cov[p];
        float* o = out + (size_t)i * 3;
        o[0] /= c; o[1] /= c; o[2] /= c;
    }
}

// ---------------- launch ----------------

extern "C" void kernel_launch(void* const* d_in, const int* in_sizes, int n_in,
                              void* d_out, int out_size, void* d_ws, size_t ws_size,
                              hipStream_t stream) {
    const float* tod     = (const float*)d_in[0];   // [B][S]
    const float* weights = (const float*)d_in[1];   // [S][3]
    const float* cov     = (const float*)d_in[2];   // [NPIX]
    const int*   pix     = (const int*)d_in[3];     // [S]
    float* out = (float*)d_out;                     // [B][NPIX][3]

    const int S    = in_sizes[3];
    const int npix = in_sizes[2];
    const int B    = in_sizes[0] / S;

    const size_t meta_ints  = (size_t)NB * NBLK + NB + (NB + 1);
    const size_t meta_bytes = ((meta_ints * sizeof(int)) + 63) & ~(size_t)63;
    const size_t need_rec   = meta_bytes + (size_t)S * 32;         // R3
    const size_t need_ridx  = meta_ints * sizeof(int) + (size_t)S * sizeof(int); // R2

    const int chunk = (S + NBLK - 1) / NBLK;

    if (B == 4 && npix == NB * BW && ws_size >= need_rec) {
        // ---- R3 payload-sort path ----
        int* hist2d = (int*)d_ws;
        int* btotal = hist2d + (size_t)NB * NBLK;
        int* bbase  = btotal + NB;
        float4* rec = (float4*)((char*)d_ws + meta_bytes);

        hist_kernel<<<NBLK, 256, 0, stream>>>(pix, S, chunk, hist2d);
        scan_blocks_kernel<<<NB, NBLK, 0, stream>>>(hist2d, btotal);
        scan_buckets_kernel<<<1, NB, 0, stream>>>(btotal, bbase, S);
        reorder_payload_kernel<<<NBLK, 256, 0, stream>>>(tod, weights, pix, S,
                                                         chunk, hist2d, bbase, rec);
        accum_rec_kernel<<<NB, BW, 0, stream>>>(rec, cov, bbase, out, npix);
        return;
    }

    if (B == 4 && npix == NB * BW && ws_size >= need_ridx) {
        // ---- R2 index-sort path ----
        int* hist2d = (int*)d_ws;
        int* btotal = hist2d + (size_t)NB * NBLK;
        int* bbase  = btotal + NB;
        int* ridx   = bbase + (NB + 1);

        hist_kernel<<<NBLK, 256, 0, stream>>>(pix, S, chunk, hist2d);
        scan_blocks_kernel<<<NB, NBLK, 0, stream>>>(hist2d, btotal);
        scan_buckets_kernel<<<1, NB, 0, stream>>>(btotal, bbase, S);
        reorder_kernel<<<NBLK, 256, 0, stream>>>(pix, S, chunk, hist2d, bbase, ridx);
        accum_kernel<<<NB, BW, 0, stream>>>(tod, weights, cov, pix, ridx, bbase,
                                            out, S, npix);
        return;
    }

    // ---- generic fallback ----
    const int block = 256;
    {
        const int n4 = out_size / 4;
        int grid = min((n4 + block - 1) / block, 2048);
        zero_out_kernel<<<grid, block, 0, stream>>>((float4*)out, n4);
    }
    {
        int grid = min((S + block - 1) / block, 4096);
        scatter_kernel<<<grid, block, 0, stream>>>(tod, weights, pix, out, S, npix, B);
    }
    {
        const int total = B * npix;
        int grid = min((total + block - 1) / block, 2048);
        normalize_kernel<<<grid, block, 0, stream>>>(out, cov, npix, B);
    }
}